// Round 1
// baseline (1403.543 us; speedup 1.0000x reference)
//
#include <hip/hip_runtime.h>
#include <hip/hip_bf16.h>

#define H 64
#define EPS 1e-5f

// One thread per edge. Full fp32. Hidden vectors live in registers
// (compile-time indexing only — runtime-indexed arrays go to scratch).
// Weight/bias/gamma/beta reads are wave-uniform -> compiler scalarizes to
// s_load; v_fmac_f32 takes the SGPR operand directly (1 sgpr read/VALU op ok).
__global__ void __launch_bounds__(256) edge_mlp_kernel(
    const float* __restrict__ pos,   // (N,3)
    const float* __restrict__ vel,   // (N,3)
    const int*   __restrict__ eidx,  // (2,E) int32
    const float* __restrict__ W1,    // (8,H) row-major
    const float* __restrict__ b1,    // (H)
    const float* __restrict__ g1,    // (H)
    const float* __restrict__ be1,   // (H)
    const float* __restrict__ W2,    // (H,H) row-major
    const float* __restrict__ b2,    // (H)
    const float* __restrict__ g2,    // (H)
    const float* __restrict__ be2,   // (H)
    float* __restrict__ out,         // (E,H)
    int E)
{
    const int e = blockIdx.x * 256 + threadIdx.x;
    if (e >= E) return;

    const int s = eidx[e];       // row 0: src
    const int t = eidx[E + e];   // row 1: tgt

    // Gather node data (1.2 MB arrays -> L2-resident random access).
    const float rx = pos[3*t+0] - pos[3*s+0];
    const float ry = pos[3*t+1] - pos[3*s+1];
    const float rz = pos[3*t+2] - pos[3*s+2];
    const float vx = vel[3*t+0] - vel[3*s+0];
    const float vy = vel[3*t+1] - vel[3*s+1];
    const float vz = vel[3*t+2] - vel[3*s+2];
    const float rn = sqrtf(rx*rx + ry*ry + rz*rz);
    const float vn = sqrtf(vx*vx + vy*vy + vz*vz);

    const float f[8] = {rx, ry, rz, rn, vx, vy, vz, vn};

    // ---- Layer 1: feats @ W1 + b1 ----
    float h[H];
#pragma unroll
    for (int j = 0; j < H; ++j) {
        float a = b1[j];
#pragma unroll
        for (int k = 0; k < 8; ++k) a = fmaf(f[k], W1[k*H + j], a);
        h[j] = a;
    }

    // ---- LayerNorm1 + ReLU (per-edge over 64 registers) ----
    {
        float m = 0.f;
#pragma unroll
        for (int j = 0; j < H; ++j) m += h[j];
        m *= (1.0f / H);
        float v = 0.f;
#pragma unroll
        for (int j = 0; j < H; ++j) { const float d = h[j] - m; v = fmaf(d, d, v); }
        v *= (1.0f / H);
        const float rs = rsqrtf(v + EPS);
#pragma unroll
        for (int j = 0; j < H; ++j) {
            const float y = fmaf((h[j] - m) * rs, g1[j], be1[j]);
            h[j] = fmaxf(y, 0.f);
        }
    }

    // ---- Layer 2: h @ W2 + b2 (64x64, fully unrolled, scalar W2 ops) ----
    float acc[H];
#pragma unroll
    for (int j = 0; j < H; ++j) acc[j] = b2[j];
#pragma unroll
    for (int k = 0; k < H; ++k) {
        const float hk = h[k];
#pragma unroll
        for (int j = 0; j < H; ++j) acc[j] = fmaf(hk, W2[k*H + j], acc[j]);
    }

    // ---- LayerNorm2 + ReLU ----
    {
        float m = 0.f;
#pragma unroll
        for (int j = 0; j < H; ++j) m += acc[j];
        m *= (1.0f / H);
        float v = 0.f;
#pragma unroll
        for (int j = 0; j < H; ++j) { const float d = acc[j] - m; v = fmaf(d, d, v); }
        v *= (1.0f / H);
        const float rs = rsqrtf(v + EPS);
#pragma unroll
        for (int j = 0; j < H; ++j) {
            const float y = fmaf((acc[j] - m) * rs, g2[j], be2[j]);
            acc[j] = fmaxf(y, 0.f);
        }
    }

    // ---- Store: 256 B contiguous per thread (full 64B-line coverage) ----
    float* o = out + (size_t)e * H;
#pragma unroll
    for (int j = 0; j < H; j += 4) {
        float4 v4 = make_float4(acc[j], acc[j+1], acc[j+2], acc[j+3]);
        *reinterpret_cast<float4*>(o + j) = v4;
    }
}

extern "C" void kernel_launch(void* const* d_in, const int* in_sizes, int n_in,
                              void* d_out, int out_size, void* d_ws, size_t ws_size,
                              hipStream_t stream) {
    const float* pos = (const float*)d_in[0];
    const float* vel = (const float*)d_in[1];
    const int*  eidx = (const int*)d_in[2];
    const float* W1  = (const float*)d_in[3];
    const float* b1  = (const float*)d_in[4];
    const float* g1  = (const float*)d_in[5];
    const float* be1 = (const float*)d_in[6];
    const float* W2  = (const float*)d_in[7];
    const float* b2  = (const float*)d_in[8];
    const float* g2  = (const float*)d_in[9];
    const float* be2 = (const float*)d_in[10];
    float* out = (float*)d_out;

    const int E = in_sizes[2] / 2;
    const int grid = (E + 255) / 256;
    edge_mlp_kernel<<<grid, 256, 0, stream>>>(pos, vel, eidx, W1, b1, g1, be1,
                                              W2, b2, g2, be2, out, E);
}